// Round 1
// baseline (170.796 us; speedup 1.0000x reference)
//
#include <hip/hip_runtime.h>

#define BB 4
#define TT 64
#define SS 256
#define DD 512

typedef __attribute__((ext_vector_type(8))) short short8;    // 8 bf16 = 4 VGPRs
typedef __attribute__((ext_vector_type(4))) float floatx4;

__device__ __forceinline__ float fast_tanh(float x) {
    x = fminf(fmaxf(x, -10.f), 10.f);
    float t = __expf(2.f * x);
    return (t - 1.f) / (t + 1.f);
}

// v_cvt_pk_bf16_f32: D.lo = bf16(lo), D.hi = bf16(hi), round-to-nearest-even —
// numerically identical to the previous cvt_kernel's pack_bf2.
__device__ __forceinline__ unsigned int cvt_pk_bf16(float lo, float hi) {
    unsigned int r;
    asm("v_cvt_pk_bf16_f32 %0, %1, %2" : "=v"(r) : "v"(lo), "v"(hi));
    return r;
}

// Load 8 consecutive fp32 (32B, 16B-aligned) and convert to a bf16 MFMA fragment.
__device__ __forceinline__ short8 load_cvt8(const float* __restrict__ p) {
    floatx4 lo = *(const floatx4*)p;
    floatx4 hi = *(const floatx4*)(p + 4);
    union { short8 s; unsigned int u[4]; } r;
    r.u[0] = cvt_pk_bf16(lo[0], lo[1]);
    r.u[1] = cvt_pk_bf16(lo[2], lo[3]);
    r.u[2] = cvt_pk_bf16(hi[0], hi[1]);
    r.u[3] = cvt_pk_bf16(hi[2], hi[3]);
    return r.s;
}

// One 64xN tile (N = NF*16) of C = tanh(A @ W^T + b).
// A:[M,K] fp32 row-major, W:[512,K] fp32 row-major, C:[M,512] fp32.
// 4 waves/block; wave = 16 rows x N cols via NF independent 16x16x32 bf16 MFMAs.
// Fragments converted fp32->bf16 in-register (no staging buffers, no LDS).
template<int NF>
__device__ __forceinline__ void gemm_tile(
    const float* __restrict__ A, const float* __restrict__ W,
    const float* __restrict__ bias, float* __restrict__ C,
    const int K, const int m0, const int n0)
{
    const int wv   = threadIdx.x >> 6;   // wave 0..3 -> 16-row stripe
    const int lane = threadIdx.x & 63;
    const int fr   = lane & 15;          // fragment row (A) / col (B)
    const int kh   = (lane >> 4) * 8;    // k sub-offset

    const float* Ap = A + (m0 + wv * 16 + fr) * K + kh;
    const float* Wp = W + (n0 + fr) * K + kh;
    const int WS = 16 * K;               // n-frag stride in W

    floatx4 acc0 = {0.f,0.f,0.f,0.f}, acc1 = acc0, acc2 = acc0, acc3 = acc0;

    short8 a  = load_cvt8(Ap);
    short8 w0 = load_cvt8(Wp);
    short8 w1 = load_cvt8(Wp + WS);
    short8 w2, w3;
    if constexpr (NF == 4) { w2 = load_cvt8(Wp + 2 * WS); w3 = load_cvt8(Wp + 3 * WS); }

    for (int k0 = 0; k0 < K; k0 += 32) {
        const int kn = (k0 + 32 < K) ? (k0 + 32) : 0;   // wrap: dummy valid prefetch on last iter
        short8 an  = load_cvt8(Ap + kn);
        short8 wn0 = load_cvt8(Wp + kn);
        short8 wn1 = load_cvt8(Wp + WS + kn);
        short8 wn2, wn3;
        if constexpr (NF == 4) { wn2 = load_cvt8(Wp + 2 * WS + kn); wn3 = load_cvt8(Wp + 3 * WS + kn); }
        acc0 = __builtin_amdgcn_mfma_f32_16x16x32_bf16(a, w0, acc0, 0, 0, 0);
        acc1 = __builtin_amdgcn_mfma_f32_16x16x32_bf16(a, w1, acc1, 0, 0, 0);
        if constexpr (NF == 4) {
            acc2 = __builtin_amdgcn_mfma_f32_16x16x32_bf16(a, w2, acc2, 0, 0, 0);
            acc3 = __builtin_amdgcn_mfma_f32_16x16x32_bf16(a, w3, acc3, 0, 0, 0);
        }
        a = an; w0 = wn0; w1 = wn1;
        if constexpr (NF == 4) { w2 = wn2; w3 = wn3; }
    }

    // C/D layout: col = lane&15, row = (lane>>4)*4 + reg   [m89-verified]
    const int orow = m0 + wv * 16 + (lane >> 4) * 4;
    const int oc0  = n0 + fr;
    const float bv0 = bias[oc0], bv1 = bias[oc0 + 16];
    float bv2 = 0.f, bv3 = 0.f;
    if constexpr (NF == 4) { bv2 = bias[oc0 + 32]; bv3 = bias[oc0 + 48]; }
    #pragma unroll
    for (int r = 0; r < 4; ++r) {
        float* Cr = C + (orow + r) * DD + oc0;
        Cr[0]  = fast_tanh(acc0[r] + bv0);
        Cr[16] = fast_tanh(acc1[r] + bv1);
        if constexpr (NF == 4) {
            Cr[32] = fast_tanh(acc2[r] + bv2);
            Cr[48] = fast_tanh(acc3[r] + bv3);
        }
    }
}

// Device-scope grid barrier. Requires all blocks co-resident (512 blocks,
// __launch_bounds__(256,2) -> 2 blocks/CU on 256 CUs). Agent-scope atomics +
// __threadfence give cross-XCD visibility (per-XCD L2s are not coherent).
// Bounded spin: a surprise fails verification instead of hanging the bench.
__device__ __forceinline__ void grid_barrier(int* __restrict__ bar, const int target) {
    __syncthreads();
    if (threadIdx.x == 0) {
        __threadfence();   // release: drain + write back this block's stores
        __hip_atomic_fetch_add(bar, 1, __ATOMIC_ACQ_REL, __HIP_MEMORY_SCOPE_AGENT);
        int spins = 0;
        while (__hip_atomic_load(bar, __ATOMIC_RELAXED, __HIP_MEMORY_SCOPE_AGENT) < target) {
            __builtin_amdgcn_s_sleep(2);
            if (++spins > (1 << 22)) break;   // safety valve (~0.25 s)
        }
        __threadfence();   // acquire: invalidate stale L1/L2 before reading peers' data
    }
    __syncthreads();
}

// ---- Fused: [4 tanh-GEMMs over 512 balanced tiles] -> barrier -> [attention]
__global__ __launch_bounds__(256, 2) void fused_kernel(
    const float* __restrict__ X,  const float* __restrict__ Z,  const float* __restrict__ Y,
    const float* __restrict__ W1, const float* __restrict__ b1,
    const float* __restrict__ W2, const float* __restrict__ b2,
    const float* __restrict__ W3, const float* __restrict__ b3,
    const float* __restrict__ W4, const float* __restrict__ b4,
    float* __restrict__ H, float* __restrict__ Fo,
    float* __restrict__ O2, float* __restrict__ O3,
    int* __restrict__ bar, float* __restrict__ out)
{
    // ---------------- Phase 1: GEMMs, exactly one tile per block (512 tiles)
    {
        const int id = blockIdx.x;
        if (id < 256) {            // H = tanh(X @ W1^T + b1), K=512: 16x16 tiles of 64x32
            gemm_tile<2>(X, W1, b1, H, 512, (id >> 4) * 64, (id & 15) * 32);
        } else if (id < 384) {     // Fo = tanh(Z @ W3^T + b3), K=128: 16x8 tiles of 64x64
            const int q = id - 256;
            gemm_tile<4>(Z, W3, b3, Fo, 128, (q >> 3) * 64, (q & 7) * 64);
        } else if (id < 448) {     // O2 = tanh(Y @ W2^T + b2), K=512: 4x16 tiles of 64x32
            const int q = id - 384;
            gemm_tile<2>(Y, W2, b2, O2, 512, (q >> 4) * 64, (q & 15) * 32);
        } else {                   // O3 = tanh(Y @ W4^T + b4), K=512: 4x16 tiles of 64x32
            const int q = id - 448;
            gemm_tile<2>(Y, W4, b4, O3, 512, (q >> 4) * 64, (q & 15) * 32);
        }
    }

    grid_barrier(bar, 512);

    // ---------------- Phase 2: attn[b,t,d] = sum_s softmax_s(H*u + F*v) * enc
    // |w| <= 2 (tanh-bounded inputs) so no max subtraction needed.
    // float4 per thread: 4 d-columns, softmax state component-wise.
    {
        const int idx = blockIdx.x;                    // 0..511
        const int b   = (idx & 7) >> 1;                // XCD-pair per batch (L2 locality)
        const int rem = ((idx >> 3) << 1) | (idx & 1); // 0..127
        const int t0  = (rem >> 2) * 2;                // t-pair
        const int dq  = rem & 3;                       // d-quarter
        const int tid = threadIdx.x;
        const int dv  = tid & 31;                      // d-vec lane (4 floats each)
        const int sg  = tid >> 5;                      // s-group 0..7 (32 s each)
        const int d   = dq * 128 + dv * 4;
        const int bt0 = b * TT + t0;

        const floatx4 u0 = *(const floatx4*)&O2[bt0 * DD + d];
        const floatx4 v0 = *(const floatx4*)&O3[bt0 * DD + d];
        const floatx4 u1 = *(const floatx4*)&O2[(bt0 + 1) * DD + d];
        const floatx4 v1 = *(const floatx4*)&O3[(bt0 + 1) * DD + d];

        floatx4 l0 = {0.f,0.f,0.f,0.f}, l1 = l0, a0 = l0, a1 = l0;
        const int base = (b * SS + sg * 32) * DD + d;
        const float* Hb = H  + base;
        const float* Fb = Fo + base;
        const float* Eb = X  + base;   // enc viewed as [B,S,E] (reference's .view trick)

        for (int s0 = 0; s0 < 32; s0 += 4) {
            floatx4 h[4], f[4], e[4];
            #pragma unroll
            for (int s = 0; s < 4; ++s) h[s] = *(const floatx4*)&Hb[(s0 + s) * DD];
            #pragma unroll
            for (int s = 0; s < 4; ++s) f[s] = *(const floatx4*)&Fb[(s0 + s) * DD];
            #pragma unroll
            for (int s = 0; s < 4; ++s) e[s] = *(const floatx4*)&Eb[(s0 + s) * DD];
            #pragma unroll
            for (int s = 0; s < 4; ++s) {
                const floatx4 w0 = h[s] * u0 + f[s] * v0;
                const floatx4 w1 = h[s] * u1 + f[s] * v1;
                floatx4 x0, x1;
                #pragma unroll
                for (int j = 0; j < 4; ++j) { x0[j] = __expf(w0[j]); x1[j] = __expf(w1[j]); }
                l0 += x0; a0 += x0 * e[s];
                l1 += x1; a1 += x1 * e[s];
            }
        }

        // Reduce 8 s-groups. Layout red[group][j][dv]: lanes dv consecutive -> conflict-free.
        __shared__ float red[7][16][32];
        if (sg != 0) {
            #pragma unroll
            for (int j = 0; j < 4; ++j) {
                red[sg - 1][j][dv]      = l0[j];
                red[sg - 1][4 + j][dv]  = l1[j];
                red[sg - 1][8 + j][dv]  = a0[j];
                red[sg - 1][12 + j][dv] = a1[j];
            }
        }
        __syncthreads();
        if (sg == 0) {
            #pragma unroll
            for (int q = 0; q < 7; ++q) {
                #pragma unroll
                for (int j = 0; j < 4; ++j) {
                    l0[j] += red[q][j][dv];
                    l1[j] += red[q][4 + j][dv];
                    a0[j] += red[q][8 + j][dv];
                    a1[j] += red[q][12 + j][dv];
                }
            }
            const floatx4 r0 = a0 / l0;
            const floatx4 r1 = a1 / l1;
            const int OFFA = BB * TT * 2 * DD;   // second output (attn) region
            *(floatx4*)&out[OFFA + bt0 * DD + d]       = r0;
            *(floatx4*)&out[OFFA + (bt0 + 1) * DD + d] = r1;
            *(floatx4*)&out[bt0 * 2 * DD + DD + d]       = r0;
            *(floatx4*)&out[(bt0 + 1) * 2 * DD + DD + d] = r1;
            *(floatx4*)&out[bt0 * 2 * DD + d]       = *(const floatx4*)&Y[bt0 * DD + d];
            *(floatx4*)&out[(bt0 + 1) * 2 * DD + d] = *(const floatx4*)&Y[(bt0 + 1) * DD + d];
        }
    }
}

extern "C" void kernel_launch(void* const* d_in, const int* in_sizes, int n_in,
                              void* d_out, int out_size, void* d_ws, size_t ws_size,
                              hipStream_t stream)
{
    const float* Y  = (const float*)d_in[0];   // output          [4,64,512]
    const float* X  = (const float*)d_in[1];   // encoder_hidden  [1024,512] flat ([S,B,E])
    const float* Z  = (const float*)d_in[2];   // input_z         [1024,128] flat ([B,S,F])
    const float* W1 = (const float*)d_in[3];
    const float* b1 = (const float*)d_in[4];
    const float* W2 = (const float*)d_in[5];
    const float* b2 = (const float*)d_in[6];
    const float* W3 = (const float*)d_in[7];
    const float* b3 = (const float*)d_in[8];
    const float* W4 = (const float*)d_in[9];
    const float* b4 = (const float*)d_in[10];
    float* out = (float*)d_out;

    int*   bar = (int*)d_ws;                 // 256B header: barrier counter
    float* H   = (float*)d_ws + 64;          // [1024,512] fp32 ([S,B,D] mem order)
    float* Fo  = H  + 1024 * 512;            // [1024,512] fp32 ([B,S,D])
    float* O2  = Fo + 1024 * 512;            // [256,512]  fp32
    float* O3  = O2 + 256 * 512;             // [256,512]  fp32

    hipMemsetAsync(bar, 0, 256, stream);     // zero barrier (ws is poisoned per-iteration)
    fused_kernel<<<512, 256, 0, stream>>>(X, Z, Y, W1, b1, W2, b2, W3, b3, W4, b4,
                                          H, Fo, O2, O3, bar, out);
}

// Round 3
// 111.964 us; speedup vs baseline: 1.5255x; 1.5255x over previous
//
#include <hip/hip_runtime.h>

#define BB 4
#define TT 64
#define SS 256
#define DD 512

typedef __attribute__((ext_vector_type(8))) short short8;    // 8 bf16 = 4 VGPRs
typedef __attribute__((ext_vector_type(4))) float floatx4;

__device__ __forceinline__ float fast_tanh(float x) {
    x = fminf(fmaxf(x, -10.f), 10.f);
    float t = __expf(2.f * x);
    return (t - 1.f) / (t + 1.f);
}

// v_cvt_pk_bf16_f32: D.lo = bf16(lo), D.hi = bf16(hi), RNE.
__device__ __forceinline__ unsigned int cvt_pk_bf16(float lo, float hi) {
    unsigned int r;
    asm("v_cvt_pk_bf16_f32 %0, %1, %2" : "=v"(r) : "v"(lo), "v"(hi));
    return r;
}

// Convert 8 fp32 (held in registers) to a bf16 MFMA fragment.
__device__ __forceinline__ short8 cvt8(floatx4 lo, floatx4 hi) {
    union { short8 s; unsigned int u[4]; } r;
    r.u[0] = cvt_pk_bf16(lo[0], lo[1]);
    r.u[1] = cvt_pk_bf16(lo[2], lo[3]);
    r.u[2] = cvt_pk_bf16(hi[0], hi[1]);
    r.u[3] = cvt_pk_bf16(hi[2], hi[3]);
    return r.s;
}

// One 64xN tile (N = NF*16) of C = tanh(A @ W^T + b).
// A:[M,K] fp32 row-major, W:[512,K] fp32 row-major, C:[M,512] fp32.
// 4 waves/block; wave = 16 rows x N cols via NF independent 16x16x32 bf16 MFMAs.
// Software pipeline: issue fp32 loads for iter k+1, convert iter k's registers
// (loads landed during iter k-1's MFMAs), MFMA. The cvt never waits on the
// loads issued in the same iteration.
template<int NF>
__device__ __forceinline__ void gemm_tile(
    const float* __restrict__ A, const float* __restrict__ W,
    const float* __restrict__ bias, float* __restrict__ C,
    const int K, const int m0, const int n0)
{
    const int wv   = threadIdx.x >> 6;   // wave 0..3 -> 16-row stripe
    const int lane = threadIdx.x & 63;
    const int fr   = lane & 15;          // fragment row (A) / col (B)
    const int kh   = (lane >> 4) * 8;    // k sub-offset

    const float* Ap = A + (m0 + wv * 16 + fr) * K + kh;
    const float* Wp = W + (n0 + fr) * K + kh;
    const int WS = 16 * K;               // n-frag stride in W

    floatx4 acc[NF];
    #pragma unroll
    for (int f = 0; f < NF; ++f) acc[f] = (floatx4){0.f, 0.f, 0.f, 0.f};

    // raw fp32 staging registers for the CURRENT iteration's fragments
    floatx4 rA0 = *(const floatx4*)Ap;
    floatx4 rA1 = *(const floatx4*)(Ap + 4);
    floatx4 rW0[NF], rW1[NF];
    #pragma unroll
    for (int f = 0; f < NF; ++f) {
        rW0[f] = *(const floatx4*)(Wp + f * WS);
        rW1[f] = *(const floatx4*)(Wp + f * WS + 4);
    }

    for (int k0 = 0; k0 < K; k0 += 32) {
        const int kn = (k0 + 32 < K) ? (k0 + 32) : 0;  // wrap: dummy valid prefetch on last iter
        floatx4 nA0 = *(const floatx4*)(Ap + kn);
        floatx4 nA1 = *(const floatx4*)(Ap + kn + 4);
        floatx4 nW0[NF], nW1[NF];
        #pragma unroll
        for (int f = 0; f < NF; ++f) {
            nW0[f] = *(const floatx4*)(Wp + f * WS + kn);
            nW1[f] = *(const floatx4*)(Wp + f * WS + kn + 4);
        }
        const short8 a = cvt8(rA0, rA1);
        #pragma unroll
        for (int f = 0; f < NF; ++f) {
            const short8 w = cvt8(rW0[f], rW1[f]);
            acc[f] = __builtin_amdgcn_mfma_f32_16x16x32_bf16(a, w, acc[f], 0, 0, 0);
        }
        rA0 = nA0; rA1 = nA1;
        #pragma unroll
        for (int f = 0; f < NF; ++f) { rW0[f] = nW0[f]; rW1[f] = nW1[f]; }
    }

    // C/D layout: col = lane&15, row = (lane>>4)*4 + reg   [m89-verified]
    const int orow = m0 + wv * 16 + (lane >> 4) * 4;
    const int oc0  = n0 + fr;
    float bv[NF];
    #pragma unroll
    for (int f = 0; f < NF; ++f) bv[f] = bias[oc0 + 16 * f];
    #pragma unroll
    for (int r = 0; r < 4; ++r) {
        float* Cr = C + (orow + r) * DD + oc0;
        #pragma unroll
        for (int f = 0; f < NF; ++f) Cr[16 * f] = fast_tanh(acc[f][r] + bv[f]);
    }
}

// ---- Kernel 1: 4 tanh-GEMMs over 512 perfectly balanced tiles, fp32 in / fp32 out,
// bf16 conversion in-register. No LDS, no barriers, no staging buffers.
__global__ __launch_bounds__(256) void gemm_kernel(
    const float* __restrict__ X,  const float* __restrict__ Z,  const float* __restrict__ Y,
    const float* __restrict__ W1, const float* __restrict__ b1,
    const float* __restrict__ W2, const float* __restrict__ b2,
    const float* __restrict__ W3, const float* __restrict__ b3,
    const float* __restrict__ W4, const float* __restrict__ b4,
    float* __restrict__ H, float* __restrict__ Fo,
    float* __restrict__ O2, float* __restrict__ O3)
{
    const int id = blockIdx.x;
    if (id < 256) {            // H = tanh(X @ W1^T + b1), K=512: 16x16 tiles of 64x32
        gemm_tile<2>(X, W1, b1, H, 512, (id >> 4) * 64, (id & 15) * 32);
    } else if (id < 384) {     // Fo = tanh(Z @ W3^T + b3), K=128: 16x8 tiles of 64x64
        const int q = id - 256;
        gemm_tile<4>(Z, W3, b3, Fo, 128, (q >> 3) * 64, (q & 7) * 64);
    } else if (id < 448) {     // O2 = tanh(Y @ W2^T + b2), K=512: 4x16 tiles of 64x32
        const int q = id - 384;
        gemm_tile<2>(Y, W2, b2, O2, 512, (q >> 4) * 64, (q & 15) * 32);
    } else {                   // O3 = tanh(Y @ W4^T + b4), K=512: 4x16 tiles of 64x32
        const int q = id - 448;
        gemm_tile<2>(Y, W4, b4, O3, 512, (q >> 4) * 64, (q & 15) * 32);
    }
}

// ---- Kernel 2: attn[b,t,d] = sum_s softmax_s(H*u + F*v) * enc, float4-vectorized.
// |w| <= 2 (tanh-bounded inputs, |u|,|v|<=1) so no max subtraction needed.
__global__ __launch_bounds__(256) void attn_kernel(
    const float* __restrict__ H, const float* __restrict__ Fo,
    const float* __restrict__ X,   // enc, [1024,512] flat
    const float* __restrict__ O2, const float* __restrict__ O3,
    const float* __restrict__ Y,   // [256,512] flat
    float* __restrict__ out)
{
    const int idx = blockIdx.x;                    // 0..511
    const int b   = (idx & 7) >> 1;                // XCD-pair per batch (L2 locality)
    const int rem = ((idx >> 3) << 1) | (idx & 1); // 0..127
    const int t0  = (rem >> 2) * 2;                // t-pair
    const int dq  = rem & 3;                       // d-quarter
    const int tid = threadIdx.x;
    const int dv  = tid & 31;                      // d-vec lane (4 floats each)
    const int sg  = tid >> 5;                      // s-group 0..7 (32 s each)
    const int d   = dq * 128 + dv * 4;
    const int bt0 = b * TT + t0;

    const floatx4 u0 = *(const floatx4*)&O2[bt0 * DD + d];
    const floatx4 v0 = *(const floatx4*)&O3[bt0 * DD + d];
    const floatx4 u1 = *(const floatx4*)&O2[(bt0 + 1) * DD + d];
    const floatx4 v1 = *(const floatx4*)&O3[(bt0 + 1) * DD + d];

    floatx4 l0 = {0.f,0.f,0.f,0.f}, l1 = l0, a0 = l0, a1 = l0;
    const int base = (b * SS + sg * 32) * DD + d;
    const float* Hb = H  + base;
    const float* Fb = Fo + base;
    const float* Eb = X  + base;   // enc viewed as [B,S,E] (reference's raw .view)

    for (int s0 = 0; s0 < 32; s0 += 4) {
        floatx4 h[4], f[4], e[4];
        #pragma unroll
        for (int s = 0; s < 4; ++s) h[s] = *(const floatx4*)&Hb[(s0 + s) * DD];
        #pragma unroll
        for (int s = 0; s < 4; ++s) f[s] = *(const floatx4*)&Fb[(s0 + s) * DD];
        #pragma unroll
        for (int s = 0; s < 4; ++s) e[s] = *(const floatx4*)&Eb[(s0 + s) * DD];
        #pragma unroll
        for (int s = 0; s < 4; ++s) {
            const floatx4 w0 = h[s] * u0 + f[s] * v0;
            const floatx4 w1 = h[s] * u1 + f[s] * v1;
            floatx4 x0, x1;
            #pragma unroll
            for (int j = 0; j < 4; ++j) { x0[j] = __expf(w0[j]); x1[j] = __expf(w1[j]); }
            l0 += x0; a0 += x0 * e[s];
            l1 += x1; a1 += x1 * e[s];
        }
    }

    // Reduce 8 s-groups. red[group][j][dv]: lanes dv consecutive -> conflict-free.
    __shared__ float red[7][16][32];
    if (sg != 0) {
        #pragma unroll
        for (int j = 0; j < 4; ++j) {
            red[sg - 1][j][dv]      = l0[j];
            red[sg - 1][4 + j][dv]  = l1[j];
            red[sg - 1][8 + j][dv]  = a0[j];
            red[sg - 1][12 + j][dv] = a1[j];
        }
    }
    __syncthreads();
    if (sg == 0) {
        #pragma unroll
        for (int q = 0; q < 7; ++q) {
            #pragma unroll
            for (int j = 0; j < 4; ++j) {
                l0[j] += red[q][j][dv];
                l1[j] += red[q][4 + j][dv];
                a0[j] += red[q][8 + j][dv];
                a1[j] += red[q][12 + j][dv];
            }
        }
        const floatx4 r0 = a0 / l0;
        const floatx4 r1 = a1 / l1;
        const int OFFA = BB * TT * 2 * DD;   // second output (attn) region
        *(floatx4*)&out[OFFA + bt0 * DD + d]       = r0;
        *(floatx4*)&out[OFFA + (bt0 + 1) * DD + d] = r1;
        *(floatx4*)&out[bt0 * 2 * DD + DD + d]       = r0;
        *(floatx4*)&out[(bt0 + 1) * 2 * DD + DD + d] = r1;
        *(floatx4*)&out[bt0 * 2 * DD + d]       = *(const floatx4*)&Y[bt0 * DD + d];
        *(floatx4*)&out[(bt0 + 1) * 2 * DD + d] = *(const floatx4*)&Y[(bt0 + 1) * DD + d];
    }
}

extern "C" void kernel_launch(void* const* d_in, const int* in_sizes, int n_in,
                              void* d_out, int out_size, void* d_ws, size_t ws_size,
                              hipStream_t stream)
{
    const float* Y  = (const float*)d_in[0];   // output          [4,64,512]
    const float* X  = (const float*)d_in[1];   // encoder_hidden  [1024,512] flat ([S,B,E])
    const float* Z  = (const float*)d_in[2];   // input_z         [1024,128] flat ([B,S,F])
    const float* W1 = (const float*)d_in[3];
    const float* b1 = (const float*)d_in[4];
    const float* W2 = (const float*)d_in[5];
    const float* b2 = (const float*)d_in[6];
    const float* W3 = (const float*)d_in[7];
    const float* b3 = (const float*)d_in[8];
    const float* W4 = (const float*)d_in[9];
    const float* b4 = (const float*)d_in[10];
    float* out = (float*)d_out;

    float* H  = (float*)d_ws;            // [1024,512] fp32 ([S,B,D] mem order)
    float* Fo = H  + 1024 * 512;         // [1024,512] fp32 ([B,S,D])
    float* O2 = Fo + 1024 * 512;         // [256,512]  fp32
    float* O3 = O2 + 256 * 512;          // [256,512]  fp32

    gemm_kernel<<<512, 256, 0, stream>>>(X, Z, Y, W1, b1, W2, b2, W3, b3, W4, b4,
                                         H, Fo, O2, O3);
    attn_kernel<<<512, 256, 0, stream>>>(H, Fo, X, O2, O3, Y, out);
}